// Round 15
// baseline (1846.522 us; speedup 1.0000x reference)
//
#include <hip/hip_runtime.h>
#include <type_traits>

typedef _Float16 f16;
typedef f16 f16x4 __attribute__((ext_vector_type(4)));
typedef f16 f16x8 __attribute__((ext_vector_type(8)));
typedef float f32x4 __attribute__((ext_vector_type(4)));
typedef unsigned int u32;

#define MFMA __builtin_amdgcn_mfma_f32_16x16x32_f16
#define WGSCOPE __HIP_MEMORY_SCOPE_WORKGROUP

constexpr int Bsz = 256, T = 512, D = 128, H = 512, C = 128;
constexpr int ROWS = 16;          // batch rows per block (MFMA M)
constexpr int TPB  = 512;         // 8 waves, 2/SIMD
constexpr int LDH  = H + 8;       // b128 bank-uniform stride
constexpr int LDX  = D + 8;
constexpr int NTG  = H / 16;      // 32 n-tiles over H
constexpr int PKT  = 8;           // Whh k-tiles pinned in regs (kt 0..7)
constexpr int KTL  = 3;           // Whh k-tiles in LDS (kt 8..10); kt 11..15 streamed
constexpr size_t XSTRIDE = (size_t)16 * NTG * 256;  // xproj elems per timestep

// Pack fp32 [K][N] row-major -> fp16 MFMA-fragment order.
// k-slot map (BIJECTION, must match load_a): k = kt*32 + 8*(lane>>4) + e.
// perm=1 (Whx/Whh): column permutation within each 64-col wave group so tile
// nt owns cols {g*64 + (nt&3) + 4m} -> C-fragment values for fixed r are
// CONTIGUOUS across nt => h-write is one ds_write_b64 per r. perm=0: plain.
__global__ void pack_w(const float* __restrict__ W, int K, int N, int perm,
                       f16* __restrict__ out) {
    int total = K * N;
    int NT = N / 16;
    for (int idx = blockIdx.x * blockDim.x + threadIdx.x; idx < total;
         idx += gridDim.x * blockDim.x) {
        int e    = idx & 7;
        int lane = (idx >> 3) & 63;
        int tile = idx >> 9;
        int kt = tile / NT, nt = tile % NT;
        int k = kt * 32 + 8 * (lane >> 4) + e;
        int m = lane & 15;
        int n = perm ? ((nt >> 2) * 64 + (nt & 3) + 4 * m) : (nt * 16 + m);
        out[idx] = (f16)W[(size_t)k * N + n];
    }
}

__device__ __forceinline__ f16x8 load_a(const f16* base, int ld, int kt, int l15, int l4) {
    return *(const f16x8*)(base + l15 * ld + kt * 32 + 8 * l4);
}

// tanh(v) = 1 - 2/(2^(v*2*log2e)+1); exp2 direct; overflow-safe.
__device__ __forceinline__ float fast_tanh(float v) {
    float e = __builtin_amdgcn_exp2f(v * 2.885390081777927f);  // 2*log2(e)
    return 1.f - __fdividef(2.f, e + 1.f);
}

// xproj = x_t @ Whx + bh in MFMA C-fragment order (f32 or f16). Runs on all CUs.
template <typename OT>
__global__ __launch_bounds__(TPB, 2) void xproj_k(
    const float* __restrict__ x, const f16* __restrict__ wpack,
    const float* __restrict__ bh, OT* __restrict__ xp) {
    const f16* Whx_p = wpack;
    __shared__ __align__(16) f16 xb[2][ROWS][LDX];
    const int tid = threadIdx.x, lane = tid & 63, w = tid >> 6;
    const int l15 = lane & 15, l4 = lane >> 4;
    const int bt = blockIdx.x;       // 0..15
    const int t0 = blockIdx.y * 16;  // chunks of 16 timesteps
    const int b0 = bt * ROWS;
    const int xrow = tid >> 5, xd0 = (tid & 31) * 4;
    const int ntg0 = w * 4;

    // permuted column meaning: tile ntg0+nt, slot l15 -> true col w*64+nt+4*l15
    float bh4[4];
#pragma unroll
    for (int nt = 0; nt < 4; nt++) bh4[nt] = bh[w * 64 + nt + 4 * l15];
    {
        float4 v = *(const float4*)&x[((size_t)(b0 + xrow) * T + t0) * D + xd0];
        f16x4 h4 = {(f16)v.x, (f16)v.y, (f16)v.z, (f16)v.w};
        *(f16x4*)&xb[0][xrow][xd0] = h4;
    }
    __syncthreads();

    int p = 0;
    for (int tt = 0; tt < 16; tt++) {
        int t = t0 + tt;
        float4 xv;
        const bool havex = (tt + 1 < 16);
        if (havex)
            xv = *(const float4*)&x[((size_t)(b0 + xrow) * T + (t + 1)) * D + xd0];
        f32x4 acc[4];
#pragma unroll
        for (int nt = 0; nt < 4; nt++)
            acc[nt] = (f32x4){bh4[nt], bh4[nt], bh4[nt], bh4[nt]};
#pragma unroll
        for (int kt = 0; kt < D / 32; kt++) {
            f16x8 a = load_a(&xb[p][0][0], LDX, kt, l15, l4);
            const f16* btp = Whx_p + (((size_t)kt * NTG + ntg0) * 64 + lane) * 8;
#pragma unroll
            for (int nt = 0; nt < 4; nt++) {
                f16x8 b = *(const f16x8*)(btp + (size_t)nt * 512);
                acc[nt] = MFMA(a, b, acc[nt], 0, 0, 0);
            }
        }
        if (havex) {
            f16x4 h4 = {(f16)xv.x, (f16)xv.y, (f16)xv.z, (f16)xv.w};
            *(f16x4*)&xb[p ^ 1][xrow][xd0] = h4;
        }
        OT* op = xp + (((size_t)t * 16 + bt) * NTG + ntg0) * 256 + (size_t)lane * 4;
#pragma unroll
        for (int nt = 0; nt < 4; nt++) {
            if constexpr (std::is_same_v<OT, float>) {
                *(f32x4*)(op + (size_t)nt * 256) = acc[nt];
            } else {
                f16x4 v = {(f16)acc[nt][0], (f16)acc[nt][1], (f16)acc[nt][2],
                           (f16)acc[nt][3]};
                *(f16x4*)(op + (size_t)nt * 256) = v;
            }
        }
        __syncthreads();
        p ^= 1;
    }
}

// XP=1: f32 xproj. XP=2: f16 xproj. XP=0: in-loop Whx fallback (barrier-synced).
// XP!=0: flag-synced, 3-ring hbuf. Streamed kt 11..15 each own a dedicated
// register buffer; CS(kt) is immediately followed by LS(kt) for the NEXT
// step into the same buffer => load-use distance = one full body (latency-
// immune regardless of L2 contention), and the body needs no 2-step unroll.
template <int XP>
__global__ __launch_bounds__(TPB, 2) void rnn_main(
    const float* __restrict__ x, const f16* __restrict__ wpack,
    const void* __restrict__ xproj, const float* __restrict__ bh,
    const float* __restrict__ bp, float* __restrict__ out) {
    const f16* Whx_p = wpack;
    const f16* Whh_p = wpack + D * H;
    const f16* Wph_p = wpack + D * H + H * H;

    __shared__ __align__(16) f16 hbuf[3][ROWS][LDH];           // 49.9 KB ring
    __shared__ __align__(16) f16 whh_lds[KTL * NTG * 64 * 8];  // 96 KB, kt 8..10
    __shared__ u32 pflag[8];  // pflag[v]=s: wave v's chunk of h_s readable
    __shared__ __align__(16) f16 xbuf[(XP == 0) ? 2 : 1][(XP == 0) ? ROWS : 1]
                                     [(XP == 0) ? LDX : 8];

    const int tid = threadIdx.x, lane = tid & 63, w = tid >> 6;
    const int l15 = lane & 15, l4 = lane >> 4;
    const int b0 = blockIdx.x * ROWS;
    const int xrow = tid >> 5, xd0 = (tid & 31) * 4;
    const int ntg0 = w * 4;

    // Pinned Whh kt 0..7 (128 regs, AGPR-resident; budget full — R9: no more).
    f16x8 wreg[PKT][4];
#pragma unroll
    for (int kt = 0; kt < PKT; kt++)
#pragma unroll
        for (int nt = 0; nt < 4; nt++)
            wreg[kt][nt] =
                *(const f16x8*)(Whh_p + (((size_t)kt * NTG + ntg0 + nt) * 64 + lane) * 8);

    // Stage Whh kt 8..10 into LDS.
    {
        const f16* src = Whh_p + (size_t)PKT * NTG * 512;
        for (int i = tid; i < KTL * NTG * 64; i += TPB)
            *(f16x8*)&whh_lds[(size_t)i * 8] = *(const f16x8*)(src + (size_t)i * 8);
    }
    for (int i = tid; i < ROWS * LDH; i += TPB) (&hbuf[0][0][0])[i] = (f16)0.f;
    if (tid < 8) pflag[tid] = 0u;  // h_0 ready

    float bh4[4];
    const float* xpf = nullptr;
    const f16* xph = nullptr;
    if constexpr (XP == 1) {
        xpf = (const float*)xproj + (((size_t)blockIdx.x * NTG + ntg0) * 64 + lane) * 4;
    } else if constexpr (XP == 2) {
        xph = (const f16*)xproj + (((size_t)blockIdx.x * NTG + ntg0) * 64 + lane) * 4;
    } else {
#pragma unroll
        for (int nt = 0; nt < 4; nt++) bh4[nt] = bh[w * 64 + nt + 4 * l15];
        float4 v = *(const float4*)&x[((size_t)(b0 + xrow) * T + 0) * D + xd0];
        f16x4 h4 = {(f16)v.x, (f16)v.y, (f16)v.z, (f16)v.w};
        *(f16x4*)&xbuf[0][xrow][xd0] = h4;
    }

    // Dedicated stream buffers, one per streamed kt (11..15): 80 arch VGPRs.
    // Prologue loads all five for step 0.
    f16x8 s11[4], s12[4], s13[4], s14[4], s15[4];
    {
        const f16* wb0 = Whh_p + ((size_t)ntg0 * 64 + lane) * 8;
#pragma unroll
        for (int nt = 0; nt < 4; nt++) {
            s11[nt] = *(const f16x8*)(wb0 + ((size_t)11 * NTG + nt) * 512);
            s12[nt] = *(const f16x8*)(wb0 + ((size_t)12 * NTG + nt) * 512);
            s13[nt] = *(const f16x8*)(wb0 + ((size_t)13 * NTG + nt) * 512);
            s14[nt] = *(const f16x8*)(wb0 + ((size_t)14 * NTG + nt) * 512);
            s15[nt] = *(const f16x8*)(wb0 + ((size_t)15 * NTG + nt) * 512);
        }
    }
    __syncthreads();  // one-time: init + pflag visible
    __builtin_amdgcn_s_setprio(1);

    // Acquire-spin on producer v (no-op for own tiles). Early-exit; on miss
    // drop prio + s_sleep per retry (issue-slot hygiene).
    auto spin = [&](int v, u32 tgt) {
        if constexpr (XP != 0) {
            if (v != w) {
                if (__hip_atomic_load(&pflag[v], __ATOMIC_ACQUIRE, WGSCOPE) >= tgt)
                    return;
                __builtin_amdgcn_s_setprio(0);
                do {
                    __builtin_amdgcn_s_sleep(1);
                } while (__hip_atomic_load(&pflag[v], __ATOMIC_ACQUIRE, WGSCOPE) < tgt);
                __builtin_amdgcn_s_setprio(1);
            }
        }
    };

    // One timestep: reads h_t from hb, writes h_{t+1} to hw.
    auto body = [&](u32 t, const f16* hb, f16* hw, int pp) {
        uintptr_t whu = (uintptr_t)Whh_p;
        asm volatile("" : "+s"(whu));  // defeat LICM on invariant weight loads
        const f16* wbase = (const f16*)whu + ((size_t)ntg0 * 64 + lane) * 8;
        u32 zo = 0;
        asm volatile("" : "+v"(zo));
        const f16x8* wlds = (const f16x8*)whh_lds + zo;

        // issue this step's xproj fragment loads (consumed pre-tanh)
        f32x4 xr32[4];
        f16x4 xr16[4];
        if constexpr (XP == 1) {
            const float* xq = xpf + (size_t)t * XSTRIDE;
#pragma unroll
            for (int nt = 0; nt < 4; nt++) xr32[nt] = *(const f32x4*)(xq + (size_t)nt * 256);
        } else if constexpr (XP == 2) {
            const f16* xq = xph + (size_t)t * XSTRIDE;
#pragma unroll
            for (int nt = 0; nt < 4; nt++) xr16[nt] = *(const f16x4*)(xq + (size_t)nt * 256);
        }

        f32x4 acc[4];
        if constexpr (XP == 0) {
#pragma unroll
            for (int nt = 0; nt < 4; nt++)
                acc[nt] = (f32x4){bh4[nt], bh4[nt], bh4[nt], bh4[nt]};
        } else {
#pragma unroll
            for (int nt = 0; nt < 4; nt++) acc[nt] = (f32x4){0.f, 0.f, 0.f, 0.f};
        }

        if constexpr (XP == 0) {
            float4 xv;
            const bool havex = (t + 1 < T);
            if (havex)
                xv = *(const float4*)&x[((size_t)(b0 + xrow) * T + (t + 1)) * D + xd0];
            uintptr_t wxu = (uintptr_t)Whx_p;
            asm volatile("" : "+s"(wxu));
            const f16* wxs = (const f16*)wxu;
#pragma unroll
            for (int kt = 0; kt < D / 32; kt++) {
                f16x8 a = load_a(&xbuf[pp][0][0], LDX, kt, l15, l4);
                const f16* bt = wxs + (((size_t)kt * NTG + ntg0) * 64 + lane) * 8;
#pragma unroll
                for (int nt = 0; nt < 4; nt++) {
                    f16x8 b = *(const f16x8*)(bt + (size_t)nt * 512);
                    acc[nt] = MFMA(a, b, acc[nt], 0, 0, 0);
                }
            }
            if (havex) {
                f16x4 h4 = {(f16)xv.x, (f16)xv.y, (f16)xv.z, (f16)xv.w};
                *(f16x4*)&xbuf[pp ^ 1][xrow][xd0] = h4;
            }
        }

        // ---- h @ Whh: pinned kt0..7 | LDS kt8..10 | streamed kt11..15 ----
        // Producer of A-fragment kt is wave kt>>1.
        auto LS = [&](int kt, f16x8(&bf)[4]) {
#pragma unroll
            for (int nt = 0; nt < 4; nt++)
                bf[nt] = *(const f16x8*)(wbase + ((size_t)kt * NTG + nt) * 512);
        };
        auto PK = [&](int kt) {
            f16x8 a = load_a(hb, LDH, kt, l15, l4);
#pragma unroll
            for (int nt = 0; nt < 4; nt++)
                acc[nt] = MFMA(a, wreg[kt][nt], acc[nt], 0, 0, 0);
        };
        auto CL = [&](int ktl) {
            f16x8 a = load_a(hb, LDH, PKT + ktl, l15, l4);
#pragma unroll
            for (int nt = 0; nt < 4; nt++)
                acc[nt] = MFMA(a, wlds[((size_t)ktl * NTG + ntg0 + nt) * 64 + lane],
                               acc[nt], 0, 0, 0);
        };
        auto CS = [&](int kt, f16x8(&bf)[4]) {
            f16x8 a = load_a(hb, LDH, kt, l15, l4);
#pragma unroll
            for (int nt = 0; nt < 4; nt++) acc[nt] = MFMA(a, bf[nt], acc[nt], 0, 0, 0);
        };

        // Uniform schedule; each CS(kt) immediately re-issues LS(kt) for the
        // next step into its dedicated buffer (full-body load-use distance).
        // Spin before FIRST use of each producer (full 8-producer coverage).
        /*pos0 */ spin(0, t); PK(0);
        /*pos1 */             PK(1);
        /*pos2 */ spin(5, t); CS(11, s11); LS(11, s11);
        /*pos3 */ spin(1, t); PK(2);
        /*pos4 */             PK(3);
        /*pos5 */ spin(6, t); CS(12, s12); LS(12, s12);
        /*pos6 */ spin(4, t); CL(0);
        /*pos7 */ spin(2, t); PK(4);
        /*pos8 */             CS(13, s13); LS(13, s13);
        /*pos9 */             PK(5);
        /*pos10*/             CL(1);
        /*pos11*/ spin(7, t); CS(14, s14); LS(14, s14);
        /*pos12*/ spin(3, t); PK(6);
        /*pos13*/             CL(2);
        /*pos14*/             CS(15, s15); LS(15, s15);
        /*pos15*/             PK(7);

        // h_new = tanh(acc [+ xproj]). Permuted col map: (nt, l15, r) ->
        // true col w*64 + nt + 4*l15 => one ds_write_b64 per r.
#pragma unroll
        for (int r = 0; r < 4; r++) {
            f16x4 hv;
#pragma unroll
            for (int nt = 0; nt < 4; nt++) {
                float v = acc[nt][r];
                if constexpr (XP == 1) v += xr32[nt][r];
                else if constexpr (XP == 2) v += (float)xr16[nt][r];
                hv[nt] = (f16)fast_tanh(v);
            }
            *(f16x4*)&hw[(l4 * 4 + r) * LDH + w * 64 + 4 * l15] = hv;
        }
        if constexpr (XP != 0) {
            if (lane == 0)
                __hip_atomic_store(&pflag[w], t + 1, __ATOMIC_RELEASE, WGSCOPE);
        } else {
            __syncthreads();
        }
    };

    f16* r0 = &hbuf[0][0][0];
    f16* r1 = &hbuf[1][0][0];
    f16* r2 = &hbuf[2][0][0];
#pragma unroll 1
    for (u32 t = 0; t < T; t++) {
        body(t, r0, r1, (int)(t & 1));
        f16* tmp = r0;
        r0 = r1;
        r1 = r2;
        r2 = tmp;  // h_{t+1} now in r0
    }
    // h_T in r0

    // wait for all waves' h_T, then out = h_T @ Wph + bp
    if constexpr (XP != 0) {
        __builtin_amdgcn_s_setprio(0);
        for (;;) {
            u32 f = __hip_atomic_load(&pflag[lane & 7], __ATOMIC_ACQUIRE, WGSCOPE);
            if (((u32)__ballot(f >= (u32)T) & 0xffu) == 0xffu) break;
            __builtin_amdgcn_s_sleep(1);
        }
        __builtin_amdgcn_s_setprio(1);
    } else {
        __syncthreads();
    }
    {
        // Wph packed plain (perm=0); h in true-column order -> unchanged.
        float bpv = bp[w * 16 + l15];
        f32x4 acc = {bpv, bpv, bpv, bpv};
#pragma unroll 4
        for (int kt = 0; kt < H / 32; kt++) {
            f16x8 a = load_a(r0, LDH, kt, l15, l4);
            f16x8 b = *(const f16x8*)(Wph_p + (((size_t)kt * (C / 16) + w) * 64 + lane) * 8);
            acc = MFMA(a, b, acc, 0, 0, 0);
        }
#pragma unroll
        for (int r = 0; r < 4; r++)
            out[(size_t)(b0 + l4 * 4 + r) * C + w * 16 + l15] = acc[r];
    }
}

extern "C" void kernel_launch(void* const* d_in, const int* in_sizes, int n_in,
                              void* d_out, int out_size, void* d_ws, size_t ws_size,
                              hipStream_t stream) {
    const float* x   = (const float*)d_in[0];
    const float* Whx = (const float*)d_in[1];
    const float* Whh = (const float*)d_in[2];
    const float* Wph = (const float*)d_in[3];
    const float* bh  = (const float*)d_in[4];
    const float* bp  = (const float*)d_in[5];

    f16* wp = (f16*)d_ws; // 768 KB packed fp16 weights
    pack_w<<<dim3(128), 256, 0, stream>>>(Whx, D, H, 1, wp);
    pack_w<<<dim3(512), 256, 0, stream>>>(Whh, H, H, 1, wp + D * H);
    pack_w<<<dim3(128), 256, 0, stream>>>(Wph, H, C, 0, wp + D * H + H * H);

    const size_t wbytes = (size_t)(D * H + H * H + H * C) * sizeof(f16); // 768 KB
    const size_t xpel   = (size_t)T * 16 * NTG * 256;                    // 67.1M elems

    if (ws_size >= wbytes + xpel * sizeof(float)) {        // 257 MB: f32 xproj
        float* xpb = (float*)((char*)d_ws + wbytes);
        xproj_k<float><<<dim3(16, T / 16), TPB, 0, stream>>>(x, wp, bh, xpb);
        rnn_main<1><<<dim3(Bsz / ROWS), TPB, 0, stream>>>(x, wp, xpb, bh, bp,
                                                          (float*)d_out);
    } else if (ws_size >= wbytes + xpel * sizeof(f16)) {   // 129 MB: f16 xproj
        f16* xpb = (f16*)((char*)d_ws + wbytes);
        xproj_k<f16><<<dim3(16, T / 16), TPB, 0, stream>>>(x, wp, bh, xpb);
        rnn_main<2><<<dim3(Bsz / ROWS), TPB, 0, stream>>>(x, wp, xpb, bh, bp,
                                                          (float*)d_out);
    } else {                                               // fallback: in-loop Whx
        rnn_main<0><<<dim3(Bsz / ROWS), TPB, 0, stream>>>(x, wp, nullptr, bh, bp,
                                                          (float*)d_out);
    }
}

// Round 16
// 1319.998 us; speedup vs baseline: 1.3989x; 1.3989x over previous
//
#include <hip/hip_runtime.h>
#include <type_traits>

typedef _Float16 f16;
typedef f16 f16x4 __attribute__((ext_vector_type(4)));
typedef f16 f16x8 __attribute__((ext_vector_type(8)));
typedef float f32x4 __attribute__((ext_vector_type(4)));
typedef unsigned int u32;

#define MFMA __builtin_amdgcn_mfma_f32_16x16x32_f16
#define WGSCOPE __HIP_MEMORY_SCOPE_WORKGROUP

constexpr int Bsz = 256, T = 512, D = 128, H = 512, C = 128;
constexpr int ROWS = 16;          // batch rows per block (MFMA M)
constexpr int TPB  = 512;         // 8 waves, 2/SIMD
constexpr int LDH  = H + 8;       // b128 bank-uniform stride
constexpr int LDX  = D + 8;
constexpr int NTG  = H / 16;      // 32 n-tiles over H
constexpr int PKT  = 8;           // Whh k-tiles pinned in regs (kt 0..7)
constexpr int KTL  = 3;           // Whh k-tiles in LDS (kt 8..10); kt 11..15 streamed
constexpr size_t XSTRIDE = (size_t)16 * NTG * 256;  // xproj elems per timestep

// Pack fp32 [K][N] row-major -> fp16 MFMA-fragment order.
// k-slot map (BIJECTION, must match load_a): k = kt*32 + 8*(lane>>4) + e.
// perm=1 (Whx/Whh): column permutation within each 64-col wave group so tile
// nt owns cols {g*64 + (nt&3) + 4m} -> C-fragment values for fixed r are
// CONTIGUOUS across nt => h-write is one ds_write_b64 per r. perm=0: plain.
__global__ void pack_w(const float* __restrict__ W, int K, int N, int perm,
                       f16* __restrict__ out) {
    int total = K * N;
    int NT = N / 16;
    for (int idx = blockIdx.x * blockDim.x + threadIdx.x; idx < total;
         idx += gridDim.x * blockDim.x) {
        int e    = idx & 7;
        int lane = (idx >> 3) & 63;
        int tile = idx >> 9;
        int kt = tile / NT, nt = tile % NT;
        int k = kt * 32 + 8 * (lane >> 4) + e;
        int m = lane & 15;
        int n = perm ? ((nt >> 2) * 64 + (nt & 3) + 4 * m) : (nt * 16 + m);
        out[idx] = (f16)W[(size_t)k * N + n];
    }
}

__device__ __forceinline__ f16x8 load_a(const f16* base, int ld, int kt, int l15, int l4) {
    return *(const f16x8*)(base + l15 * ld + kt * 32 + 8 * l4);
}

// tanh(v) = 1 - 2/(2^(v*2*log2e)+1); exp2 direct; overflow-safe.
__device__ __forceinline__ float fast_tanh(float v) {
    float e = __builtin_amdgcn_exp2f(v * 2.885390081777927f);  // 2*log2(e)
    return 1.f - __fdividef(2.f, e + 1.f);
}

// xproj = x_t @ Whx + bh in MFMA C-fragment order (f32 or f16). Runs on all CUs.
template <typename OT>
__global__ __launch_bounds__(TPB, 2) void xproj_k(
    const float* __restrict__ x, const f16* __restrict__ wpack,
    const float* __restrict__ bh, OT* __restrict__ xp) {
    const f16* Whx_p = wpack;
    __shared__ __align__(16) f16 xb[2][ROWS][LDX];
    const int tid = threadIdx.x, lane = tid & 63, w = tid >> 6;
    const int l15 = lane & 15, l4 = lane >> 4;
    const int bt = blockIdx.x;       // 0..15
    const int t0 = blockIdx.y * 16;  // chunks of 16 timesteps
    const int b0 = bt * ROWS;
    const int xrow = tid >> 5, xd0 = (tid & 31) * 4;
    const int ntg0 = w * 4;

    // permuted column meaning: tile ntg0+nt, slot l15 -> true col w*64+nt+4*l15
    float bh4[4];
#pragma unroll
    for (int nt = 0; nt < 4; nt++) bh4[nt] = bh[w * 64 + nt + 4 * l15];
    {
        float4 v = *(const float4*)&x[((size_t)(b0 + xrow) * T + t0) * D + xd0];
        f16x4 h4 = {(f16)v.x, (f16)v.y, (f16)v.z, (f16)v.w};
        *(f16x4*)&xb[0][xrow][xd0] = h4;
    }
    __syncthreads();

    int p = 0;
    for (int tt = 0; tt < 16; tt++) {
        int t = t0 + tt;
        float4 xv;
        const bool havex = (tt + 1 < 16);
        if (havex)
            xv = *(const float4*)&x[((size_t)(b0 + xrow) * T + (t + 1)) * D + xd0];
        f32x4 acc[4];
#pragma unroll
        for (int nt = 0; nt < 4; nt++)
            acc[nt] = (f32x4){bh4[nt], bh4[nt], bh4[nt], bh4[nt]};
#pragma unroll
        for (int kt = 0; kt < D / 32; kt++) {
            f16x8 a = load_a(&xb[p][0][0], LDX, kt, l15, l4);
            const f16* btp = Whx_p + (((size_t)kt * NTG + ntg0) * 64 + lane) * 8;
#pragma unroll
            for (int nt = 0; nt < 4; nt++) {
                f16x8 b = *(const f16x8*)(btp + (size_t)nt * 512);
                acc[nt] = MFMA(a, b, acc[nt], 0, 0, 0);
            }
        }
        if (havex) {
            f16x4 h4 = {(f16)xv.x, (f16)xv.y, (f16)xv.z, (f16)xv.w};
            *(f16x4*)&xb[p ^ 1][xrow][xd0] = h4;
        }
        OT* op = xp + (((size_t)t * 16 + bt) * NTG + ntg0) * 256 + (size_t)lane * 4;
#pragma unroll
        for (int nt = 0; nt < 4; nt++) {
            if constexpr (std::is_same_v<OT, float>) {
                *(f32x4*)(op + (size_t)nt * 256) = acc[nt];
            } else {
                f16x4 v = {(f16)acc[nt][0], (f16)acc[nt][1], (f16)acc[nt][2],
                           (f16)acc[nt][3]};
                *(f16x4*)(op + (size_t)nt * 256) = v;
            }
        }
        __syncthreads();
        p ^= 1;
    }
}

// XP=1: f32 xproj. XP=2: f16 xproj. XP=0: in-loop Whx fallback (barrier-synced).
// XP!=0: no per-step barrier — producer/consumer LDS flags + 3-ring hbuf
// (RING 3 beats 2: slack absorbs publish/consume jitter — R13 A/B).
// Stream tiles use the 2-buffer ping-pong (32 VGPRs): R15 proved deeper
// register prefetch spills (WRITE_SIZE 128->864 KB scratch traffic).
template <int XP>
__global__ __launch_bounds__(TPB, 2) void rnn_main(
    const float* __restrict__ x, const f16* __restrict__ wpack,
    const void* __restrict__ xproj, const float* __restrict__ bh,
    const float* __restrict__ bp, float* __restrict__ out) {
    const f16* Whx_p = wpack;
    const f16* Whh_p = wpack + D * H;
    const f16* Wph_p = wpack + D * H + H * H;

    __shared__ __align__(16) f16 hbuf[3][ROWS][LDH];           // 49.9 KB ring
    __shared__ __align__(16) f16 whh_lds[KTL * NTG * 64 * 8];  // 96 KB, kt 8..10
    __shared__ u32 pflag[8];  // pflag[v]=s: wave v's chunk of h_s readable
    __shared__ __align__(16) f16 xbuf[(XP == 0) ? 2 : 1][(XP == 0) ? ROWS : 1]
                                     [(XP == 0) ? LDX : 8];

    const int tid = threadIdx.x, lane = tid & 63, w = tid >> 6;
    const int l15 = lane & 15, l4 = lane >> 4;
    const int b0 = blockIdx.x * ROWS;
    const int xrow = tid >> 5, xd0 = (tid & 31) * 4;
    const int ntg0 = w * 4;

    // Pinned Whh kt 0..7 (128 regs, AGPR-resident; budget full — R9: no more).
    f16x8 wreg[PKT][4];
#pragma unroll
    for (int kt = 0; kt < PKT; kt++)
#pragma unroll
        for (int nt = 0; nt < 4; nt++)
            wreg[kt][nt] =
                *(const f16x8*)(Whh_p + (((size_t)kt * NTG + ntg0 + nt) * 64 + lane) * 8);

    // Stage Whh kt 8..10 into LDS.
    {
        const f16* src = Whh_p + (size_t)PKT * NTG * 512;
        for (int i = tid; i < KTL * NTG * 64; i += TPB)
            *(f16x8*)&whh_lds[(size_t)i * 8] = *(const f16x8*)(src + (size_t)i * 8);
    }
    for (int i = tid; i < ROWS * LDH; i += TPB) (&hbuf[0][0][0])[i] = (f16)0.f;
    if (tid < 8) pflag[tid] = 0u;  // h_0 ready

    float bh4[4];
    const float* xpf = nullptr;
    const f16* xph = nullptr;
    if constexpr (XP == 1) {
        xpf = (const float*)xproj + (((size_t)blockIdx.x * NTG + ntg0) * 64 + lane) * 4;
    } else if constexpr (XP == 2) {
        xph = (const f16*)xproj + (((size_t)blockIdx.x * NTG + ntg0) * 64 + lane) * 4;
    } else {
#pragma unroll
        for (int nt = 0; nt < 4; nt++) bh4[nt] = bh[w * 64 + nt + 4 * l15];
        float4 v = *(const float4*)&x[((size_t)(b0 + xrow) * T + 0) * D + xd0];
        f16x4 h4 = {(f16)v.x, (f16)v.y, (f16)v.z, (f16)v.w};
        *(f16x4*)&xbuf[0][xrow][xd0] = h4;
    }

    // Prologue: preload streamed kt 11 -> sA, kt 12 -> sB.
    f16x8 sA[4], sB[4];
    {
        const f16* wb0 = Whh_p + ((size_t)ntg0 * 64 + lane) * 8;
#pragma unroll
        for (int nt = 0; nt < 4; nt++)
            sA[nt] = *(const f16x8*)(wb0 + ((size_t)11 * NTG + nt) * 512);
#pragma unroll
        for (int nt = 0; nt < 4; nt++)
            sB[nt] = *(const f16x8*)(wb0 + ((size_t)12 * NTG + nt) * 512);
    }
    __syncthreads();  // one-time: init + pflag visible
    __builtin_amdgcn_s_setprio(1);

    // Acquire-spin on producer v (no-op for own tiles). Early-exit; on miss
    // drop prio + s_sleep per retry (issue-slot hygiene).
    auto spin = [&](int v, u32 tgt) {
        if constexpr (XP != 0) {
            if (v != w) {
                if (__hip_atomic_load(&pflag[v], __ATOMIC_ACQUIRE, WGSCOPE) >= tgt)
                    return;
                __builtin_amdgcn_s_setprio(0);
                do {
                    __builtin_amdgcn_s_sleep(1);
                } while (__hip_atomic_load(&pflag[v], __ATOMIC_ACQUIRE, WGSCOPE) < tgt);
                __builtin_amdgcn_s_setprio(1);
            }
        }
    };

    // One timestep: reads h_t from hb, writes h_{t+1} to hw.
    // Entry: bA=kt11, bB=kt12 prefetched. Exit: bA=kt12', bB=kt11' (roles swap).
    auto body = [&](u32 t, const f16* hb, f16* hw, f16x8(&bA)[4], f16x8(&bB)[4],
                    int pp) {
        uintptr_t whu = (uintptr_t)Whh_p;
        asm volatile("" : "+s"(whu));  // defeat LICM on invariant weight loads
        const f16* wbase = (const f16*)whu + ((size_t)ntg0 * 64 + lane) * 8;
        u32 zo = 0;
        asm volatile("" : "+v"(zo));
        const f16x8* wlds = (const f16x8*)whh_lds + zo;

        // issue this step's xproj fragment loads (consumed pre-tanh)
        f32x4 xr32[4];
        f16x4 xr16[4];
        if constexpr (XP == 1) {
            const float* xq = xpf + (size_t)t * XSTRIDE;
#pragma unroll
            for (int nt = 0; nt < 4; nt++) xr32[nt] = *(const f32x4*)(xq + (size_t)nt * 256);
        } else if constexpr (XP == 2) {
            const f16* xq = xph + (size_t)t * XSTRIDE;
#pragma unroll
            for (int nt = 0; nt < 4; nt++) xr16[nt] = *(const f16x4*)(xq + (size_t)nt * 256);
        }

        f32x4 acc[4];
        if constexpr (XP == 0) {
#pragma unroll
            for (int nt = 0; nt < 4; nt++)
                acc[nt] = (f32x4){bh4[nt], bh4[nt], bh4[nt], bh4[nt]};
        } else {
#pragma unroll
            for (int nt = 0; nt < 4; nt++) acc[nt] = (f32x4){0.f, 0.f, 0.f, 0.f};
        }

        if constexpr (XP == 0) {
            float4 xv;
            const bool havex = (t + 1 < T);
            if (havex)
                xv = *(const float4*)&x[((size_t)(b0 + xrow) * T + (t + 1)) * D + xd0];
            uintptr_t wxu = (uintptr_t)Whx_p;
            asm volatile("" : "+s"(wxu));
            const f16* wxs = (const f16*)wxu;
#pragma unroll
            for (int kt = 0; kt < D / 32; kt++) {
                f16x8 a = load_a(&xbuf[pp][0][0], LDX, kt, l15, l4);
                const f16* bt = wxs + (((size_t)kt * NTG + ntg0) * 64 + lane) * 8;
#pragma unroll
                for (int nt = 0; nt < 4; nt++) {
                    f16x8 b = *(const f16x8*)(bt + (size_t)nt * 512);
                    acc[nt] = MFMA(a, b, acc[nt], 0, 0, 0);
                }
            }
            if (havex) {
                f16x4 h4 = {(f16)xv.x, (f16)xv.y, (f16)xv.z, (f16)xv.w};
                *(f16x4*)&xbuf[pp ^ 1][xrow][xd0] = h4;
            }
        }

        // ---- h @ Whh: pinned kt0..7 | LDS kt8..10 | streamed kt11..15 ----
        // Producer of A-fragment kt is wave kt>>1.
        auto LS = [&](int kt, f16x8(&bf)[4]) {
#pragma unroll
            for (int nt = 0; nt < 4; nt++)
                bf[nt] = *(const f16x8*)(wbase + ((size_t)kt * NTG + nt) * 512);
        };
        auto PK = [&](int kt) {
            f16x8 a = load_a(hb, LDH, kt, l15, l4);
#pragma unroll
            for (int nt = 0; nt < 4; nt++)
                acc[nt] = MFMA(a, wreg[kt][nt], acc[nt], 0, 0, 0);
        };
        auto CL = [&](int ktl) {
            f16x8 a = load_a(hb, LDH, PKT + ktl, l15, l4);
#pragma unroll
            for (int nt = 0; nt < 4; nt++)
                acc[nt] = MFMA(a, wlds[((size_t)ktl * NTG + ntg0 + nt) * 64 + lane],
                               acc[nt], 0, 0, 0);
        };
        auto CS = [&](int kt, f16x8(&bf)[4]) {
            f16x8 a = load_a(hb, LDH, kt, l15, l4);
#pragma unroll
            for (int nt = 0; nt < 4; nt++) acc[nt] = MFMA(a, bf[nt], acc[nt], 0, 0, 0);
        };

        // Uniform schedule: all streams at >=6-position load-use distance; CLs
        // interleaved where streams would stall; spin before FIRST use of
        // each producer (full 8-producer coverage).
        /*pos0 */ spin(0, t); PK(0);
        /*pos1 */             PK(1);
        /*pos2 */ spin(5, t); CS(11, bA); LS(13, bA);
        /*pos3 */ spin(1, t); PK(2);
        /*pos4 */             PK(3);
        /*pos5 */ spin(6, t); CS(12, bB); LS(14, bB);
        /*pos6 */ spin(4, t); CL(0);
        /*pos7 */ spin(2, t); PK(4);
        /*pos8 */             CS(13, bA); LS(15, bA);
        /*pos9 */             PK(5);
        /*pos10*/             CL(1);
        /*pos11*/ spin(7, t); CS(14, bB); LS(11, bB);   // next-step kt11
        /*pos12*/ spin(3, t); PK(6);
        /*pos13*/             CL(2);
        /*pos14*/             CS(15, bA); LS(12, bA);   // next-step kt12
        /*pos15*/             PK(7);

        // h_new = tanh(acc [+ xproj]). Permuted col map: (nt, l15, r) ->
        // true col w*64 + nt + 4*l15 => one ds_write_b64 per r.
#pragma unroll
        for (int r = 0; r < 4; r++) {
            f16x4 hv;
#pragma unroll
            for (int nt = 0; nt < 4; nt++) {
                float v = acc[nt][r];
                if constexpr (XP == 1) v += xr32[nt][r];
                else if constexpr (XP == 2) v += (float)xr16[nt][r];
                hv[nt] = (f16)fast_tanh(v);
            }
            *(f16x4*)&hw[(l4 * 4 + r) * LDH + w * 64 + 4 * l15] = hv;
        }
        if constexpr (XP != 0) {
            if (lane == 0)
                __hip_atomic_store(&pflag[w], t + 1, __ATOMIC_RELEASE, WGSCOPE);
        } else {
            __syncthreads();
        }
    };

    f16* r0 = &hbuf[0][0][0];
    f16* r1 = &hbuf[1][0][0];
    f16* r2 = &hbuf[2][0][0];
    for (u32 t = 0; t < T; t += 2) {
        body(t,     r0, r1, sA, sB, 0);  // exit: sB=kt11', sA=kt12'
        body(t + 1, r1, r2, sB, sA, 1);  // exit: sA=kt11'', sB=kt12''
        f16* n0 = r2; f16* n1 = r0; f16* n2 = r1;  // 3-ring rotate by 2
        r0 = n0; r1 = n1; r2 = n2;
    }
    // after loop h_T sits in r0 (T even)

    // wait for all waves' h_T, then out = h_T @ Wph + bp
    if constexpr (XP != 0) {
        __builtin_amdgcn_s_setprio(0);
        for (;;) {
            u32 f = __hip_atomic_load(&pflag[lane & 7], __ATOMIC_ACQUIRE, WGSCOPE);
            if (((u32)__ballot(f >= (u32)T) & 0xffu) == 0xffu) break;
            __builtin_amdgcn_s_sleep(1);
        }
        __builtin_amdgcn_s_setprio(1);
    } else {
        __syncthreads();
    }
    {
        // Wph packed plain (perm=0); h in true-column order -> unchanged.
        float bpv = bp[w * 16 + l15];
        f32x4 acc = {bpv, bpv, bpv, bpv};
#pragma unroll 4
        for (int kt = 0; kt < H / 32; kt++) {
            f16x8 a = load_a(r0, LDH, kt, l15, l4);
            f16x8 b = *(const f16x8*)(Wph_p + (((size_t)kt * (C / 16) + w) * 64 + lane) * 8);
            acc = MFMA(a, b, acc, 0, 0, 0);
        }
#pragma unroll
        for (int r = 0; r < 4; r++)
            out[(size_t)(b0 + l4 * 4 + r) * C + w * 16 + l15] = acc[r];
    }
}

extern "C" void kernel_launch(void* const* d_in, const int* in_sizes, int n_in,
                              void* d_out, int out_size, void* d_ws, size_t ws_size,
                              hipStream_t stream) {
    const float* x   = (const float*)d_in[0];
    const float* Whx = (const float*)d_in[1];
    const float* Whh = (const float*)d_in[2];
    const float* Wph = (const float*)d_in[3];
    const float* bh  = (const float*)d_in[4];
    const float* bp  = (const float*)d_in[5];

    f16* wp = (f16*)d_ws; // 768 KB packed fp16 weights
    pack_w<<<dim3(128), 256, 0, stream>>>(Whx, D, H, 1, wp);
    pack_w<<<dim3(512), 256, 0, stream>>>(Whh, H, H, 1, wp + D * H);
    pack_w<<<dim3(128), 256, 0, stream>>>(Wph, H, C, 0, wp + D * H + H * H);

    const size_t wbytes = (size_t)(D * H + H * H + H * C) * sizeof(f16); // 768 KB
    const size_t xpel   = (size_t)T * 16 * NTG * 256;                    // 67.1M elems

    if (ws_size >= wbytes + xpel * sizeof(float)) {        // 257 MB: f32 xproj
        float* xpb = (float*)((char*)d_ws + wbytes);
        xproj_k<float><<<dim3(16, T / 16), TPB, 0, stream>>>(x, wp, bh, xpb);
        rnn_main<1><<<dim3(Bsz / ROWS), TPB, 0, stream>>>(x, wp, xpb, bh, bp,
                                                          (float*)d_out);
    } else if (ws_size >= wbytes + xpel * sizeof(f16)) {   // 129 MB: f16 xproj
        f16* xpb = (f16*)((char*)d_ws + wbytes);
        xproj_k<f16><<<dim3(16, T / 16), TPB, 0, stream>>>(x, wp, bh, xpb);
        rnn_main<2><<<dim3(Bsz / ROWS), TPB, 0, stream>>>(x, wp, xpb, bh, bp,
                                                          (float*)d_out);
    } else {                                               // fallback: in-loop Whx
        rnn_main<0><<<dim3(Bsz / ROWS), TPB, 0, stream>>>(x, wp, nullptr, bh, bp,
                                                          (float*)d_out);
    }
}